// Round 15
// baseline (1558.637 us; speedup 1.0000x reference)
//
#include <hip/hip_runtime.h>

#define T_STEPS 2048
#define NBATCH  1024
#define L2E     1.442695040888963f

typedef _Float16 f16x8 __attribute__((ext_vector_type(8)));
typedef float    f32x4 __attribute__((ext_vector_type(4)));

// pack 2 floats -> 2 fp16 (RTZ) as one u32
__device__ __forceinline__ unsigned pk2(float a, float b) {
    auto v = __builtin_amdgcn_cvt_pkrtz(a, b);
    return __builtin_bit_cast(unsigned, v);
}

// load 8 consecutive fp32 -> 8 fp16 (RNE) fragment
__device__ __forceinline__ f16x8 loadrow8(const float* p) {
    float4 lo = *reinterpret_cast<const float4*>(p);
    float4 hi = *reinterpret_cast<const float4*>(p + 4);
    f16x8 r;
    r[0] = (_Float16)lo.x; r[1] = (_Float16)lo.y;
    r[2] = (_Float16)lo.z; r[3] = (_Float16)lo.w;
    r[4] = (_Float16)hi.x; r[5] = (_Float16)hi.y;
    r[6] = (_Float16)hi.z; r[7] = (_Float16)hi.w;
    return r;
}

// LDS-only barrier (no vmcnt drain -> x prefetch stays in flight)
__device__ __forceinline__ void sync_lds() {
    asm volatile("s_waitcnt lgkmcnt(0)" ::: "memory");
    __builtin_amdgcn_s_barrier();
    asm volatile("" ::: "memory");
}

// Pin an f16x8 into VGPRs (opaque origin -> no remat/reload in the loop)
#define PIN8(f) do { uint4 _u = __builtin_bit_cast(uint4, (f));              \
    asm volatile("" : "+v"(_u.x), "+v"(_u.y), "+v"(_u.z), "+v"(_u.w));       \
    (f) = __builtin_bit_cast(f16x8, _u); } while (0)

// 3 waves per block, one LSTM layer per wave, 16 batch columns per block,
// TWO time-steps per barrier interval, deep-skew handoffs (consume data
// written 2 intervals ago; pre-read at top of interval -> latency hidden).
// Self-recurrent h stays in registers. MFMA layout (verified R6): lane l,
// tile m holds i,f,g,o of unit 8*(l>>4)+m for batch l&15; the lane's 8
// per-tile h results ARE its next B-fragment.
// Skew: iter n = {L0: t=2n,2n+1 | L1: t=2n-4,2n-3 | L2: t=2n-8,2n-7 (+FC)}.
// ACT in STAGED SoA form: each stage = 8-32 independent ops -> cross-m-tile
// ILP hides per-op latency (R14's serial per-tile chains were the wall).
__global__ __launch_bounds__(192, 1)
void lstm3_ws3s_kernel(const float* __restrict__ x,
                       const float* __restrict__ Wih0, const float* __restrict__ Whh0,
                       const float* __restrict__ bih0, const float* __restrict__ bhh0,
                       const float* __restrict__ Wih1, const float* __restrict__ Whh1,
                       const float* __restrict__ bih1, const float* __restrict__ bhh1,
                       const float* __restrict__ Wih2, const float* __restrict__ Whh2,
                       const float* __restrict__ bih2, const float* __restrict__ bhh2,
                       const float* __restrict__ Wfc,  const float* __restrict__ bfc,
                       float* __restrict__ out)
{
    const int tid = threadIdx.x;
    const int lay = tid >> 6;         // 0..2 = layer
    const int l   = tid & 63;
    const int g   = l >> 4;           // lane group (k-chunk / C row-group)
    const int b   = l & 15;           // batch column
    const int qa  = l & 3;            // gate index for A-row loads
    const int gp  = (l & 15) >> 2;    // unit group for A-row loads
    const int b0  = blockIdx.x * 16;

    __shared__ __align__(16) f16x8 hF0[3][2][64];   // h0 handoff [slot][step][lane]
    __shared__ __align__(16) f16x8 hF1[3][2][64];   // h1 handoff

    // ---- weight fragments -> registers (pinned) ----
    f16x8 Fi[8], Fh[8];
    {
        const int rowA = qa * 32 + 8 * gp;
        const float* Pi = (lay == 1) ? Wih1 : ((lay == 2) ? Wih2 : nullptr);
        const float* Ph = (lay == 0) ? Whh0 : ((lay == 1) ? Whh1 : Whh2);
#pragma unroll
        for (int m = 0; m < 8; ++m) {
            Fh[m] = loadrow8(Ph + (rowA + m) * 32 + 8 * g);
            PIN8(Fh[m]);
        }
        if (lay != 0) {
#pragma unroll
            for (int m = 0; m < 8; ++m) {
                Fi[m] = loadrow8(Pi + (rowA + m) * 32 + 8 * g);
                PIN8(Fi[m]);
            }
        }
    }

    // ---- biases / Wih0 / Wfc -> registers (pre-scaled by +/-log2e) ----
    float4 bs[8], w0s[8];
    float wfc_r[8];
    {
        const float* BI = (lay == 0) ? bih0 : ((lay == 1) ? bih1 : bih2);
        const float* BH = (lay == 0) ? bhh0 : ((lay == 1) ? bhh1 : bhh2);
#pragma unroll
        for (int m = 0; m < 8; ++m) {
            const int u = 8 * g + m;
            const float bx = BI[u]      + BH[u];
            const float by = BI[u + 32] + BH[u + 32];
            const float bz = BI[u + 64] + BH[u + 64];
            const float bw = BI[u + 96] + BH[u + 96];
            bs[m] = make_float4(-L2E * bx, -L2E * by, 2.f * L2E * bz, -L2E * bw);
            if (lay == 0)
                w0s[m] = make_float4(-L2E * Wih0[u],          -L2E * Wih0[u + 32],
                                     2.f * L2E * Wih0[u + 64], -L2E * Wih0[u + 96]);
            if (lay == 2) wfc_r[m] = Wfc[u];
        }
    }
    const float bfc0 = bfc[0];

    if (lay == 0) {
        f16x8 zz = {0, 0, 0, 0, 0, 0, 0, 0};
        hF0[0][0][l] = zz; hF0[0][1][l] = zz;
        hF0[1][0][l] = zz; hF0[1][1][l] = zz;
        hF0[2][0][l] = zz; hF0[2][1][l] = zz;
    } else if (lay == 1) {
        f16x8 zz = {0, 0, 0, 0, 0, 0, 0, 0};
        hF1[0][0][l] = zz; hF1[0][1][l] = zz;
        hF1[1][0][l] = zz; hF1[1][1][l] = zz;
        hF1[2][0][l] = zz; hF1[2][1][l] = zz;
    }
    __syncthreads();

    float cst[8];
#pragma unroll
    for (int m = 0; m < 8; ++m) cst[m] = 0.f;
    f16x8 hself = {0, 0, 0, 0, 0, 0, 0, 0};   // own layer's h (register)
    f16x8 curA = hself, curB = hself;         // consumed handoff (2-iv-old)
    f16x8 nxtA = hself, nxtB = hself;

    float xvA = 0.f, xvB = 0.f;
    if (lay == 0) { xvA = x[b0 + b]; xvB = x[NBATCH + b0 + b]; }

    // STAGED fused-rcp LSTM step: acc[8] -> cst/hself (+fcv for lay2).
    // Each stage is a full unrolled pass over all 8 m-tiles -> 8-32
    // independent ops per stage; trans latency hidden by siblings.
#define ACT_STEP(USE_X, XV)                                                  \
    do {                                                                     \
        float t0[8], t1[8], t2[8], t3[8];                                    \
        _Pragma("unroll")                                                    \
        for (int m = 0; m < 8; ++m) {                                        \
            t0[m] = fmaf(-L2E,      acc[m][0], bs[m].x);                     \
            t1[m] = fmaf(-L2E,      acc[m][1], bs[m].y);                     \
            t2[m] = fmaf(2.f * L2E, acc[m][2], bs[m].z);                     \
            t3[m] = fmaf(-L2E,      acc[m][3], bs[m].w);                     \
        }                                                                    \
        if (USE_X) {                                                         \
            _Pragma("unroll")                                                \
            for (int m = 0; m < 8; ++m) {                                    \
                t0[m] = fmaf(w0s[m].x, (XV), t0[m]);                         \
                t1[m] = fmaf(w0s[m].y, (XV), t1[m]);                         \
                t2[m] = fmaf(w0s[m].z, (XV), t2[m]);                         \
                t3[m] = fmaf(w0s[m].w, (XV), t3[m]);                         \
            }                                                                \
        }                                                                    \
        float e0[8], e1[8], e2[8], e3[8];                                    \
        _Pragma("unroll")                                                    \
        for (int m = 0; m < 8; ++m) {                                        \
            e0[m] = __builtin_amdgcn_exp2f(t0[m]);                           \
            e1[m] = __builtin_amdgcn_exp2f(t1[m]);                           \
            e2[m] = __builtin_amdgcn_exp2f(t2[m]);                           \
            e3[m] = __builtin_amdgcn_exp2f(t3[m]);                           \
        }                                                                    \
        float dg[8], ff[8];                                                  \
        _Pragma("unroll")                                                    \
        for (int m = 0; m < 8; ++m) {                                        \
            dg[m] = __builtin_amdgcn_rcpf((1.f + e0[m]) * (1.f + e2[m]));    \
            ff[m] = __builtin_amdgcn_rcpf(1.f + e1[m]);                      \
        }                                                                    \
        float tc[8];                                                         \
        _Pragma("unroll")                                                    \
        for (int m = 0; m < 8; ++m) {                                        \
            cst[m] = fmaf(ff[m], cst[m], (e2[m] - 1.f) * dg[m]);             \
            tc[m]  = fminf(2.f * L2E * cst[m], 60.f);                        \
        }                                                                    \
        float ec[8];                                                         \
        _Pragma("unroll")                                                    \
        for (int m = 0; m < 8; ++m) ec[m] = __builtin_amdgcn_exp2f(tc[m]);   \
        float hn[8];                                                         \
        _Pragma("unroll")                                                    \
        for (int m = 0; m < 8; ++m)                                          \
            hn[m] = (ec[m] - 1.f) *                                          \
                __builtin_amdgcn_rcpf((1.f + e3[m]) * (1.f + ec[m]));        \
        uint4 pk;                                                            \
        pk.x = pk2(hn[0], hn[1]); pk.y = pk2(hn[2], hn[3]);                  \
        pk.z = pk2(hn[4], hn[5]); pk.w = pk2(hn[6], hn[7]);                  \
        hself = __builtin_bit_cast(f16x8, pk);                               \
        fcv = 0.f;                                                           \
        if (lay == 2) {                                                      \
            _Pragma("unroll")                                                \
            for (int m = 0; m < 8; ++m) fcv = fmaf(wfc_r[m], hn[m], fcv);    \
        }                                                                    \
    } while (0)

    const int NIT = T_STEPS / 2 + 4;     // 1028
    int sw = 0, sp = 2;                  // write slot n%3; pre-read slot (n-1)%3
    for (int n = 0; n < NIT; ++n) {
        f32x4 acc[8];
        float fcv;
        if (lay == 0) {
            // ========== L0: t=2n, 2n+1 (self-chain fully in-register) =====
            if (n < T_STEPS / 2) {
                const int tp = 2 * n + 2;
                const int tA = (tp     < T_STEPS) ? tp     : T_STEPS - 1;
                const int tB = (tp + 1 < T_STEPS) ? tp + 1 : T_STEPS - 1;
                const float xnA = x[tA * NBATCH + b0 + b];   // prefetch
                const float xnB = x[tB * NBATCH + b0 + b];
#pragma unroll
                for (int m = 0; m < 8; ++m) {
                    f32x4 z = {0.f, 0.f, 0.f, 0.f};
                    acc[m] = __builtin_amdgcn_mfma_f32_16x16x32_f16(Fh[m], hself, z, 0, 0, 0);
                }
                ACT_STEP(1, xvA);
                hF0[sw][0][l] = hself;
#pragma unroll
                for (int m = 0; m < 8; ++m) {
                    f32x4 z = {0.f, 0.f, 0.f, 0.f};
                    acc[m] = __builtin_amdgcn_mfma_f32_16x16x32_f16(Fh[m], hself, z, 0, 0, 0);
                }
                ACT_STEP(1, xvB);
                hF0[sw][1][l] = hself;
                xvA = xnA; xvB = xnB;
            }
        } else if (lay == 1) {
            // ===== L1: t=2n-4, 2n-3 (consumes hF0 written at n-2, in regs) =
            nxtA = hF0[sp][0][l];        // pre-read for interval n+1
            nxtB = hF0[sp][1][l];
            if (n >= 2 && n <= T_STEPS / 2 + 1) {
#pragma unroll
                for (int m = 0; m < 8; ++m) {
                    f32x4 z = {0.f, 0.f, 0.f, 0.f};
                    z      = __builtin_amdgcn_mfma_f32_16x16x32_f16(Fi[m], curA, z, 0, 0, 0);
                    acc[m] = __builtin_amdgcn_mfma_f32_16x16x32_f16(Fh[m], hself, z, 0, 0, 0);
                }
                ACT_STEP(0, 0.f);
                hF1[sw][0][l] = hself;
#pragma unroll
                for (int m = 0; m < 8; ++m) {
                    f32x4 z = {0.f, 0.f, 0.f, 0.f};
                    z      = __builtin_amdgcn_mfma_f32_16x16x32_f16(Fi[m], curB, z, 0, 0, 0);
                    acc[m] = __builtin_amdgcn_mfma_f32_16x16x32_f16(Fh[m], hself, z, 0, 0, 0);
                }
                ACT_STEP(0, 0.f);
                hF1[sw][1][l] = hself;
            }
        } else {
            // ==== L2: t=2n-8, 2n-7 (consumes hF1 written at n-2) + FC =====
            nxtA = hF1[sp][0][l];        // pre-read for interval n+1
            nxtB = hF1[sp][1][l];
            if (n >= 4 && n <= T_STEPS / 2 + 3) {
#pragma unroll
                for (int m = 0; m < 8; ++m) {
                    f32x4 z = {0.f, 0.f, 0.f, 0.f};
                    z      = __builtin_amdgcn_mfma_f32_16x16x32_f16(Fi[m], curA, z, 0, 0, 0);
                    acc[m] = __builtin_amdgcn_mfma_f32_16x16x32_f16(Fh[m], hself, z, 0, 0, 0);
                }
                ACT_STEP(0, 0.f);
                {
                    float v = fcv;
                    v += __shfl_xor(v, 16);
                    v += __shfl_xor(v, 32);
                    if (l < 16) out[(2 * n - 8) * NBATCH + b0 + l] = v + bfc0;
                }
#pragma unroll
                for (int m = 0; m < 8; ++m) {
                    f32x4 z = {0.f, 0.f, 0.f, 0.f};
                    z      = __builtin_amdgcn_mfma_f32_16x16x32_f16(Fi[m], curB, z, 0, 0, 0);
                    acc[m] = __builtin_amdgcn_mfma_f32_16x16x32_f16(Fh[m], hself, z, 0, 0, 0);
                }
                ACT_STEP(0, 0.f);
                {
                    float v = fcv;
                    v += __shfl_xor(v, 16);
                    v += __shfl_xor(v, 32);
                    if (l < 16) out[(2 * n - 7) * NBATCH + b0 + l] = v + bfc0;
                }
            }
        }

        sync_lds();                   // pre-reads complete; slot lifetimes:
                                      // write n, pre-read n+1, rewrite n+3
        curA = nxtA; curB = nxtB;
        sp = sw; sw = (sw == 2) ? 0 : sw + 1;
    }
#undef ACT_STEP
}

extern "C" void kernel_launch(void* const* d_in, const int* in_sizes, int n_in,
                              void* d_out, int out_size, void* d_ws, size_t ws_size,
                              hipStream_t stream)
{
    const float* x    = (const float*)d_in[0];
    const float* Wih0 = (const float*)d_in[1];
    const float* Whh0 = (const float*)d_in[2];
    const float* bih0 = (const float*)d_in[3];
    const float* bhh0 = (const float*)d_in[4];
    const float* Wih1 = (const float*)d_in[5];
    const float* Whh1 = (const float*)d_in[6];
    const float* bih1 = (const float*)d_in[7];
    const float* bhh1 = (const float*)d_in[8];
    const float* Wih2 = (const float*)d_in[9];
    const float* Whh2 = (const float*)d_in[10];
    const float* bih2 = (const float*)d_in[11];
    const float* bhh2 = (const float*)d_in[12];
    const float* Wfc  = (const float*)d_in[13];
    const float* bfc  = (const float*)d_in[14];
    float* out        = (float*)d_out;

    lstm3_ws3s_kernel<<<dim3(NBATCH / 16), dim3(192), 0, stream>>>(
        x, Wih0, Whh0, bih0, bhh0,
        Wih1, Whh1, bih1, bhh1,
        Wih2, Whh2, bih2, bhh2,
        Wfc, bfc, out);
}